// Round 5
// baseline (525.040 us; speedup 1.0000x reference)
//
#include <hip/hip_runtime.h>

// SDPA, static mask (kv < 2048 attended). Two-kernel plan:
//  Pass 1: K -> f16 [kv][d] rows (256B), chunk c at c ^ key(r),
//          key(r) = (r&7) ^ ((r>>1)&4); V -> f16 transposed [d][kv] via
//          LDS transpose; output chunk y of row d at y ^ (d&7).
//  Pass 2: flash attention, BM=256, 8 waves = 4 wq x 2 dh, q=64/wave.
//          Wave (wq,dh): S^T for kv-half dh (permuted-K feed -> P lane-local)
//          then PV over its OWN kv-half for FULL d=128 -- no P exchange,
//          no barrier between softmax and PV (pure register dataflow),
//          ONE __syncthreads per K-tile. R3/R4 showed 2 barriers/iter +
//          pex round-trip pinned MfmaUtil at 32% regardless of occupancy/
//          LDS traffic; this removes that block-wide serialization.
//          Partial-O halves merged once in epilogue via 32KB LDS exchange.
//          o[4][8]+bq[4][4] = 192 persistent VGPRs; __launch_bounds__(512,2)
//          -> 256-reg cap, 1 block/CU (R1's spill was the 128-reg cap).
//          Spill tripwire: WRITE_SIZE > 32768 KB.

#define NT 32

typedef _Float16 half8  __attribute__((ext_vector_type(8)));
typedef __fp16   fp16x2 __attribute__((ext_vector_type(2)));
typedef float    floatx4 __attribute__((ext_vector_type(4)));
typedef unsigned int uint;
typedef uint     uintx4 __attribute__((ext_vector_type(4)));

#if __has_builtin(__builtin_amdgcn_exp2f)
#define EXP2(x) __builtin_amdgcn_exp2f(x)
#else
#define EXP2(x) exp2f(x)
#endif

union H2U { fp16x2 h; uint u; };
union H8U { uint u[4]; half8 h; };

static __device__ __forceinline__ uint pk(float a, float b) {
    H2U z; z.h = __builtin_amdgcn_cvt_pkrtz(a, b); return z.u;
}

// ws layout (bytes): Kh[32][2048][128] f16 @0 ; Vt[32][128][2048] f16 @16MB
#define KH_BH 524288u
#define VT_BASE 16777216u
#define VT_BH 524288u

#define GLOAD_LDS16(g, l)                                                     \
    __builtin_amdgcn_global_load_lds(                                         \
        (const __attribute__((address_space(1))) uint*)(const void*)(g),      \
        (__attribute__((address_space(3))) uint*)(void*)(l), 16, 0, 0)

// ---------------- Pass 1: convert + transpose, coalesced ----------------
__global__ __launch_bounds__(256)
void cvt_kernel(const float* __restrict__ K, const float* __restrict__ V,
                char* __restrict__ ws) {
    const int bid = blockIdx.x;        // 32 bh x 32 kv-tiles of 64
    const int bh  = bid >> 5;
    const int kv0 = (bid & 31) * 64;
    const int t   = threadIdx.x;

    const float* Kb = K + (size_t)bh * 4096 * 128 + (size_t)kv0 * 128;
    const float* Vb = V + (size_t)bh * 4096 * 128 + (size_t)kv0 * 128;
    char* Khb = ws + (size_t)bh * KH_BH + (size_t)kv0 * 256;
    char* Vtb = ws + VT_BASE + (size_t)bh * VT_BH;

    // --- K: 16 lanes per 256B row; chunk c16 stored at c16 ^ key(r).
    {
        const int c16 = t & 15;
        #pragma unroll
        for (int rnd = 0; rnd < 4; ++rnd) {
            const int r = rnd * 16 + (t >> 4);
            const float* src = Kb + (size_t)r * 128 + c16 * 8;
            floatx4 a = *(const floatx4*)src;
            floatx4 b = *(const floatx4*)(src + 4);
            H8U hh;
            hh.u[0] = pk(a[0], a[1]); hh.u[1] = pk(a[2], a[3]);
            hh.u[2] = pk(b[0], b[1]); hh.u[3] = pk(b[2], b[3]);
            const int key = (r & 7) ^ ((r >> 1) & 4);
            *(half8*)(Khb + r * 256 + 16 * (c16 ^ key)) = hh.h;
        }
    }

    // --- V transpose via LDS. U[d][col] uints; col-group includes d>>2 so
    // stage-A write banks spread. Stage-B undoes it; global layout stays:
    // chunk y of row d at y ^ (d&7).
    __shared__ __align__(16) uint U[128 * 32];
    {
        const int dpos = t & 31;        // d / 4
        const int k3   = t >> 5;        // kv-pair within round
        #pragma unroll
        for (int rnd = 0; rnd < 4; ++rnd) {
            const int kvp = rnd * 8 + k3;   // kv pair index 0..31
            floatx4 a = *(const floatx4*)(Vb + (size_t)(2 * kvp) * 128 + 4 * dpos);
            floatx4 b = *(const floatx4*)(Vb + (size_t)(2 * kvp + 1) * 128 + 4 * dpos);
            #pragma unroll
            for (int e = 0; e < 4; ++e) {
                const int d   = 4 * dpos + e;
                const int col = (kvp & 3) |
                                ((((kvp >> 2) ^ d ^ (d >> 2)) & 7) << 2);
                U[d * 32 + col] = pk(a[e], b[e]);
            }
        }
    }
    __syncthreads();
    // Stage B: 8 lanes cover a full 128B Vt row.
    {
        const int s = t & 7;
        #pragma unroll
        for (int rnd = 0; rnd < 4; ++rnd) {
            const int d = rnd * 32 + (t >> 3);
            uintx4 u = *(const uintx4*)&U[d * 32 + 4 * s];
            *(uintx4*)(Vtb + (size_t)d * 4096 + (size_t)kv0 * 2 +
                       16 * ((s ^ (d >> 2)) & 7)) = u;
        }
    }
}

// ---------------- Pass 2: flash attention ----------------
__global__ __launch_bounds__(512, 2)
void fa_kernel(const float* __restrict__ Q, float* __restrict__ O,
               const char* __restrict__ ws) {
    const float SCALE = 0.08838834764831845f * 1.4426950408889634f;

    __shared__ __align__(16) char smem[65536];
    // [0,32K): kbuf[2]  [32K,64K): vbuf[2]
    // epilogue reuse: lbuf = smem (2KB), xch = smem+32K (32KB)

    const int t    = threadIdx.x;
    const int lane = t & 63;
    const int w    = t >> 6;        // 0..7
    const int wq   = w & 3;         // q-group (64 rows)
    const int dh   = w >> 2;        // kv-half (S^T+PV) / d-half (output)
    const int c    = lane & 15;
    const int qd   = lane >> 4;

    const int idx  = blockIdx.x;    // 256 = 8 xcd x 8 qt x 4 bh-group
    const int xcd  = idx & 7;
    const int slot = idx >> 3;      // 0..31
    const int qt   = slot & 7;
    const int bh   = xcd + 8 * (slot >> 3);
    const int q0   = qt * 256;

    const float* Qb  = Q + (size_t)bh * 2048 * 128;
    float*       Ob  = O + (size_t)bh * 2048 * 128;
    const char*  Khb = ws + (size_t)bh * KH_BH;
    const char*  Vtb = ws + VT_BASE + (size_t)bh * VT_BH;

    char* const kb0 = smem;
    char* const vb0 = smem + 32768;

    // K tile 16KB: 16 insts of 1KB, inst i = rows 4i..4i+3 (linear dst)
    #define ISSUE_K(kv0_, dst_)                                                  \
        { _Pragma("unroll")                                                      \
          for (int j = 0; j < 2; ++j) {                                          \
              const int i = 2 * w + j;                                           \
              const char* g = Khb + (size_t)(kv0_) * 256 +                       \
                              (size_t)(4 * i + (lane >> 4)) * 256 + (lane & 15) * 16; \
              GLOAD_LDS16(g, (dst_) + i * 1024); } }
    // V tile 16KB: inst i = d-rows 8i..8i+7 (128B each)
    #define ISSUE_V(kv0_, dst_)                                                  \
        { _Pragma("unroll")                                                      \
          for (int j = 0; j < 2; ++j) {                                          \
              const int i = 2 * w + j;                                           \
              const char* g = Vtb + (size_t)(8 * i + (lane >> 3)) * 4096 +       \
                              (size_t)(kv0_) * 2 + (lane & 7) * 16;              \
              GLOAD_LDS16(g, (dst_) + i * 1024); } }

    ISSUE_K(0, kb0);            // staging flies under Q-frag load/convert
    ISSUE_V(0, vb0);

    // ---- Q B-frags: B[k=32s+8qd+j][n=16m+c], scale folded; q=64/wave ----
    half8 bq[4][4];
    #pragma unroll
    for (int m = 0; m < 4; ++m) {
        #pragma unroll
        for (int s = 0; s < 4; ++s) {
            const int row = q0 + 64 * wq + 16 * m + c;
            const float* p = Qb + (size_t)row * 128 + 32 * s + 8 * qd;
            floatx4 x = *(const floatx4*)p;
            floatx4 y = *(const floatx4*)(p + 4);
            H8U hh;
            hh.u[0] = pk(x[0] * SCALE, x[1] * SCALE);
            hh.u[1] = pk(x[2] * SCALE, x[3] * SCALE);
            hh.u[2] = pk(y[0] * SCALE, y[1] * SCALE);
            hh.u[3] = pk(y[2] * SCALE, y[3] * SCALE);
            bq[m][s] = hh.h;
        }
    }

    // partial O^T over own kv-half, FULL d: lane (c,qd):
    //   q = 64wq+16m+c, d = 16dt+4qd+r  (dt 0..7)
    floatx4 o[4][8];
    float lsum[4] = {0.f, 0.f, 0.f, 0.f};
    #pragma unroll
    for (int m = 0; m < 4; ++m)
        #pragma unroll
        for (int dt = 0; dt < 8; ++dt) o[m][dt] = (floatx4){0.f, 0.f, 0.f, 0.f};

    __syncthreads();   // tile 0 resident

    for (int kt = 0; kt < NT; ++kt) {
        const int cur = kt & 1;
        char* kcur = kb0 + cur * 16384;
        char* vcur = vb0 + cur * 16384;
        if (kt + 1 < NT) {                     // full-iteration window
            ISSUE_K((kt + 1) * 64, kb0 + (1 - cur) * 16384);
            ISSUE_V((kt + 1) * 64, vb0 + (1 - cur) * 16384);
        }

        // ---- S^T = K Q^T on kv-half dh, permuted K-row feed:
        // C row i fed with K row 32dh + 8(i>>2) + 4g + (i&3), so lane
        // (c,qd) reg (g,r) holds kv = 32dh + 8qd + 4g + r (lane-local P).
        floatx4 st[2][4];
        #pragma unroll
        for (int g = 0; g < 2; ++g)
            #pragma unroll
            for (int m = 0; m < 4; ++m) st[g][m] = (floatx4){0.f, 0.f, 0.f, 0.f};

        __builtin_amdgcn_s_setprio(1);
        #pragma unroll
        for (int g = 0; g < 2; ++g) {
            const int row = 32 * dh + 8 * (c >> 2) + 4 * g + (c & 3);
            const int key = (row & 7) ^ ((row >> 1) & 4);
            #pragma unroll
            for (int s = 0; s < 4; ++s) {
                half8 ka = *(const half8*)(kcur + row * 256 + 16 * ((4 * s + qd) ^ key));
                #pragma unroll
                for (int m = 0; m < 4; ++m)
                    st[g][m] = __builtin_amdgcn_mfma_f32_16x16x32_f16(ka, bq[m][s], st[g][m], 0, 0, 0);
            }
        }
        __builtin_amdgcn_s_setprio(0);

        // ---- softmax (fixed m=0, exp2 domain): pb[m] el j = P[kv=32dh+8qd+j]
        // then PV immediately -- pure register dataflow, NO barrier.
        half8 pb[4];
        #pragma unroll
        for (int m = 0; m < 4; ++m) {
            const float p0 = EXP2(st[0][m][0]);
            const float p1 = EXP2(st[0][m][1]);
            const float p2 = EXP2(st[0][m][2]);
            const float p3 = EXP2(st[0][m][3]);
            const float p4 = EXP2(st[1][m][0]);
            const float p5 = EXP2(st[1][m][1]);
            const float p6 = EXP2(st[1][m][2]);
            const float p7 = EXP2(st[1][m][3]);
            lsum[m] += ((p0 + p1) + (p2 + p3)) + ((p4 + p5) + (p6 + p7));
            H8U hh;
            hh.u[0] = pk(p0, p1); hh.u[1] = pk(p2, p3);
            hh.u[2] = pk(p4, p5); hh.u[3] = pk(p6, p7);
            pb[m] = hh.h;
        }

        // ---- O^T(full d) += V^T P^T over own kv-half dh ----
        __builtin_amdgcn_s_setprio(1);
        #pragma unroll
        for (int dt = 0; dt < 8; ++dt) {
            const int d = 16 * dt + c;
            half8 va = *(const half8*)(vcur + d * 128 + 16 * ((4 * dh + qd) ^ (d & 7)));
            #pragma unroll
            for (int m = 0; m < 4; ++m)
                o[m][dt] = __builtin_amdgcn_mfma_f32_16x16x32_f16(va, pb[m], o[m][dt], 0, 0, 0);
        }
        __builtin_amdgcn_s_setprio(0);

        __syncthreads();   // next K/V tile resident; cur free for kt+2 staging
    }

    // ---- epilogue ----
    // 1) denominators: reduce lsum over qd; merge halves via lbuf
    #pragma unroll
    for (int m = 0; m < 4; ++m) {
        lsum[m] += __shfl_xor(lsum[m], 16, 64);
        lsum[m] += __shfl_xor(lsum[m], 32, 64);
    }
    float* lbuf = (float*)smem;          // [2][256] -- kbuf free after loop
    char* const xch = smem + 32768;      // 32KB     -- vbuf free after loop
    if (qd == 0) {
        #pragma unroll
        for (int m = 0; m < 4; ++m)
            lbuf[dh * 256 + 64 * wq + 16 * m + c] = lsum[m];
    }
    __syncthreads();

    // 2) O merge: per m, each wave ships the d-half it does NOT output to
    //    its slot; reads sibling's slot for the half it DOES output.
    //    Wave (wq,dh) outputs d in [64dh, 64dh+64) i.e. dt in {4dh..4dh+3}.
    #pragma unroll
    for (int m = 0; m < 4; ++m) {
        const int qrow = 64 * wq + 16 * m + c;
        const float invl = 1.0f / (lbuf[qrow] + lbuf[256 + qrow]);
        #pragma unroll
        for (int dtl = 0; dtl < 4; ++dtl) {   // ship other half
            const int dt_w = 4 * (1 - dh) + dtl;
            *(floatx4*)(xch + (w << 12) + (dtl << 10) + (lane << 4)) = o[m][dt_w];
        }
        __syncthreads();
        #pragma unroll
        for (int dtl = 0; dtl < 4; ++dtl) {   // combine + store own half
            const int dt_o = 4 * dh + dtl;
            floatx4 r = o[m][dt_o] +
                *(const floatx4*)(xch + ((w ^ 4) << 12) + (dtl << 10) + (lane << 4));
            r[0] *= invl; r[1] *= invl; r[2] *= invl; r[3] *= invl;
            *(floatx4*)&Ob[(size_t)(q0 + qrow) * 128 + 16 * dt_o + 4 * qd] = r;
        }
        __syncthreads();   // slots reusable for next m
    }
}

extern "C" void kernel_launch(void* const* d_in, const int* in_sizes, int n_in,
                              void* d_out, int out_size, void* d_ws, size_t ws_size,
                              hipStream_t stream) {
    const float* q = (const float*)d_in[0];
    const float* k = (const float*)d_in[1];
    const float* v = (const float*)d_in[2];
    float* out = (float*)d_out;
    char* ws = (char*)d_ws;
    cvt_kernel<<<dim3(1024), dim3(256), 0, stream>>>(k, v, ws);
    fa_kernel<<<dim3(256), dim3(512), 0, stream>>>(q, out, ws);
}

// Round 6
// 246.760 us; speedup vs baseline: 2.1277x; 2.1277x over previous
//
#include <hip/hip_runtime.h>

// SDPA, static mask (kv < 2048 attended). Two-kernel plan:
//  Pass 1: K -> f16 [kv][d] rows (256B), chunk c at c ^ key(r),
//          key(r) = (r&7) ^ ((r>>1)&4); V -> f16 transposed [d][kv] via
//          LDS transpose; output chunk y of row d at y ^ (d&7).
//  Pass 2: flash attention, BM=256, 8 waves = 4 wq x 2 dh, q=64/wave.
//          Wave (wq,dh): S^T for kv-half dh (permuted-K feed -> P lane-local)
//          then PV over its OWN kv-half for FULL d=128 -- no P exchange,
//          ONE __syncthreads per K-tile (R4 showed the 2-barrier pex
//          lockstep pinned MfmaUtil at 32%).
//          Partial-O halves merged once in epilogue via 32KB LDS exchange.
//          R5 LESSON (rule #20): epilogue indexed o[m][4*(1-dh)+dtl] --
//          runtime index -> o demoted to scratch for the WHOLE kernel ->
//          2.2GB spill traffic, MfmaUtil 7%. Fix: static indices, select
//          VALUES by dh (ternary), never indices.
//          o[4][8]+bq[4][4] = 192 persistent VGPRs; __launch_bounds__(512,2)
//          -> 256-reg cap, 1 block/CU. Spill tripwire: WRITE_SIZE > 32768 KB.

#define NT 32

typedef _Float16 half8  __attribute__((ext_vector_type(8)));
typedef __fp16   fp16x2 __attribute__((ext_vector_type(2)));
typedef float    floatx4 __attribute__((ext_vector_type(4)));
typedef unsigned int uint;
typedef uint     uintx4 __attribute__((ext_vector_type(4)));

#if __has_builtin(__builtin_amdgcn_exp2f)
#define EXP2(x) __builtin_amdgcn_exp2f(x)
#else
#define EXP2(x) exp2f(x)
#endif

union H2U { fp16x2 h; uint u; };
union H8U { uint u[4]; half8 h; };

static __device__ __forceinline__ uint pk(float a, float b) {
    H2U z; z.h = __builtin_amdgcn_cvt_pkrtz(a, b); return z.u;
}

// ws layout (bytes): Kh[32][2048][128] f16 @0 ; Vt[32][128][2048] f16 @16MB
#define KH_BH 524288u
#define VT_BASE 16777216u
#define VT_BH 524288u

#define GLOAD_LDS16(g, l)                                                     \
    __builtin_amdgcn_global_load_lds(                                         \
        (const __attribute__((address_space(1))) uint*)(const void*)(g),      \
        (__attribute__((address_space(3))) uint*)(void*)(l), 16, 0, 0)

// ---------------- Pass 1: convert + transpose, coalesced ----------------
__global__ __launch_bounds__(256)
void cvt_kernel(const float* __restrict__ K, const float* __restrict__ V,
                char* __restrict__ ws) {
    const int bid = blockIdx.x;        // 32 bh x 32 kv-tiles of 64
    const int bh  = bid >> 5;
    const int kv0 = (bid & 31) * 64;
    const int t   = threadIdx.x;

    const float* Kb = K + (size_t)bh * 4096 * 128 + (size_t)kv0 * 128;
    const float* Vb = V + (size_t)bh * 4096 * 128 + (size_t)kv0 * 128;
    char* Khb = ws + (size_t)bh * KH_BH + (size_t)kv0 * 256;
    char* Vtb = ws + VT_BASE + (size_t)bh * VT_BH;

    // --- K: 16 lanes per 256B row; chunk c16 stored at c16 ^ key(r).
    {
        const int c16 = t & 15;
        #pragma unroll
        for (int rnd = 0; rnd < 4; ++rnd) {
            const int r = rnd * 16 + (t >> 4);
            const float* src = Kb + (size_t)r * 128 + c16 * 8;
            floatx4 a = *(const floatx4*)src;
            floatx4 b = *(const floatx4*)(src + 4);
            H8U hh;
            hh.u[0] = pk(a[0], a[1]); hh.u[1] = pk(a[2], a[3]);
            hh.u[2] = pk(b[0], b[1]); hh.u[3] = pk(b[2], b[3]);
            const int key = (r & 7) ^ ((r >> 1) & 4);
            *(half8*)(Khb + r * 256 + 16 * (c16 ^ key)) = hh.h;
        }
    }

    // --- V transpose via LDS. U[d][col] uints; col-group includes d>>2 so
    // stage-A write banks spread. Stage-B undoes it; global layout stays:
    // chunk y of row d at y ^ (d&7).
    __shared__ __align__(16) uint U[128 * 32];
    {
        const int dpos = t & 31;        // d / 4
        const int k3   = t >> 5;        // kv-pair within round
        #pragma unroll
        for (int rnd = 0; rnd < 4; ++rnd) {
            const int kvp = rnd * 8 + k3;   // kv pair index 0..31
            floatx4 a = *(const floatx4*)(Vb + (size_t)(2 * kvp) * 128 + 4 * dpos);
            floatx4 b = *(const floatx4*)(Vb + (size_t)(2 * kvp + 1) * 128 + 4 * dpos);
            #pragma unroll
            for (int e = 0; e < 4; ++e) {
                const int d   = 4 * dpos + e;
                const int col = (kvp & 3) |
                                ((((kvp >> 2) ^ d ^ (d >> 2)) & 7) << 2);
                U[d * 32 + col] = pk(a[e], b[e]);
            }
        }
    }
    __syncthreads();
    // Stage B: 8 lanes cover a full 128B Vt row.
    {
        const int s = t & 7;
        #pragma unroll
        for (int rnd = 0; rnd < 4; ++rnd) {
            const int d = rnd * 32 + (t >> 3);
            uintx4 u = *(const uintx4*)&U[d * 32 + 4 * s];
            *(uintx4*)(Vtb + (size_t)d * 4096 + (size_t)kv0 * 2 +
                       16 * ((s ^ (d >> 2)) & 7)) = u;
        }
    }
}

// ---------------- Pass 2: flash attention ----------------
__global__ __launch_bounds__(512, 2)
void fa_kernel(const float* __restrict__ Q, float* __restrict__ O,
               const char* __restrict__ ws) {
    const float SCALE = 0.08838834764831845f * 1.4426950408889634f;

    __shared__ __align__(16) char smem[65536];
    // [0,32K): kbuf[2]  [32K,64K): vbuf[2]
    // epilogue reuse: lbuf = smem (2KB), xch = smem+32K (32KB)

    const int t    = threadIdx.x;
    const int lane = t & 63;
    const int w    = t >> 6;        // 0..7
    const int wq   = w & 3;         // q-group (64 rows)
    const int dh   = w >> 2;        // kv-half (S^T+PV) / d-half (output)
    const int c    = lane & 15;
    const int qd   = lane >> 4;

    const int idx  = blockIdx.x;    // 256 = 8 xcd x 8 qt x 4 bh-group
    const int xcd  = idx & 7;
    const int slot = idx >> 3;      // 0..31
    const int qt   = slot & 7;
    const int bh   = xcd + 8 * (slot >> 3);
    const int q0   = qt * 256;

    const float* Qb  = Q + (size_t)bh * 2048 * 128;
    float*       Ob  = O + (size_t)bh * 2048 * 128;
    const char*  Khb = ws + (size_t)bh * KH_BH;
    const char*  Vtb = ws + VT_BASE + (size_t)bh * VT_BH;

    char* const kb0 = smem;
    char* const vb0 = smem + 32768;

    // K tile 16KB: 16 insts of 1KB, inst i = rows 4i..4i+3 (linear dst)
    #define ISSUE_K(kv0_, dst_)                                                  \
        { _Pragma("unroll")                                                      \
          for (int j = 0; j < 2; ++j) {                                          \
              const int i = 2 * w + j;                                           \
              const char* g = Khb + (size_t)(kv0_) * 256 +                       \
                              (size_t)(4 * i + (lane >> 4)) * 256 + (lane & 15) * 16; \
              GLOAD_LDS16(g, (dst_) + i * 1024); } }
    // V tile 16KB: inst i = d-rows 8i..8i+7 (128B each)
    #define ISSUE_V(kv0_, dst_)                                                  \
        { _Pragma("unroll")                                                      \
          for (int j = 0; j < 2; ++j) {                                          \
              const int i = 2 * w + j;                                           \
              const char* g = Vtb + (size_t)(8 * i + (lane >> 3)) * 4096 +       \
                              (size_t)(kv0_) * 2 + (lane & 7) * 16;              \
              GLOAD_LDS16(g, (dst_) + i * 1024); } }

    ISSUE_K(0, kb0);            // staging flies under Q-frag load/convert
    ISSUE_V(0, vb0);

    // ---- Q B-frags: B[k=32s+8qd+j][n=16m+c], scale folded; q=64/wave ----
    half8 bq[4][4];
    #pragma unroll
    for (int m = 0; m < 4; ++m) {
        #pragma unroll
        for (int s = 0; s < 4; ++s) {
            const int row = q0 + 64 * wq + 16 * m + c;
            const float* p = Qb + (size_t)row * 128 + 32 * s + 8 * qd;
            floatx4 x = *(const floatx4*)p;
            floatx4 y = *(const floatx4*)(p + 4);
            H8U hh;
            hh.u[0] = pk(x[0] * SCALE, x[1] * SCALE);
            hh.u[1] = pk(x[2] * SCALE, x[3] * SCALE);
            hh.u[2] = pk(y[0] * SCALE, y[1] * SCALE);
            hh.u[3] = pk(y[2] * SCALE, y[3] * SCALE);
            bq[m][s] = hh.h;
        }
    }

    // partial O^T over own kv-half, FULL d: lane (c,qd):
    //   q = 64wq+16m+c, d = 16dt+4qd+r  (dt 0..7)
    floatx4 o[4][8];
    float lsum[4] = {0.f, 0.f, 0.f, 0.f};
    #pragma unroll
    for (int m = 0; m < 4; ++m)
        #pragma unroll
        for (int dt = 0; dt < 8; ++dt) o[m][dt] = (floatx4){0.f, 0.f, 0.f, 0.f};

    __syncthreads();   // tile 0 resident

    for (int kt = 0; kt < NT; ++kt) {
        const int cur = kt & 1;
        char* kcur = kb0 + cur * 16384;
        char* vcur = vb0 + cur * 16384;
        if (kt + 1 < NT) {                     // full-iteration window
            ISSUE_K((kt + 1) * 64, kb0 + (1 - cur) * 16384);
            ISSUE_V((kt + 1) * 64, vb0 + (1 - cur) * 16384);
        }

        // ---- S^T = K Q^T on kv-half dh, permuted K-row feed:
        // C row i fed with K row 32dh + 8(i>>2) + 4g + (i&3), so lane
        // (c,qd) reg (g,r) holds kv = 32dh + 8qd + 4g + r (lane-local P).
        floatx4 st[2][4];
        #pragma unroll
        for (int g = 0; g < 2; ++g)
            #pragma unroll
            for (int m = 0; m < 4; ++m) st[g][m] = (floatx4){0.f, 0.f, 0.f, 0.f};

        __builtin_amdgcn_s_setprio(1);
        #pragma unroll
        for (int g = 0; g < 2; ++g) {
            const int row = 32 * dh + 8 * (c >> 2) + 4 * g + (c & 3);
            const int key = (row & 7) ^ ((row >> 1) & 4);
            #pragma unroll
            for (int s = 0; s < 4; ++s) {
                half8 ka = *(const half8*)(kcur + row * 256 + 16 * ((4 * s + qd) ^ key));
                #pragma unroll
                for (int m = 0; m < 4; ++m)
                    st[g][m] = __builtin_amdgcn_mfma_f32_16x16x32_f16(ka, bq[m][s], st[g][m], 0, 0, 0);
            }
        }
        __builtin_amdgcn_s_setprio(0);

        // ---- softmax (fixed m=0, exp2 domain): pb[m] el j = P[kv=32dh+8qd+j]
        // then PV immediately -- pure register dataflow, NO barrier.
        half8 pb[4];
        #pragma unroll
        for (int m = 0; m < 4; ++m) {
            const float p0 = EXP2(st[0][m][0]);
            const float p1 = EXP2(st[0][m][1]);
            const float p2 = EXP2(st[0][m][2]);
            const float p3 = EXP2(st[0][m][3]);
            const float p4 = EXP2(st[1][m][0]);
            const float p5 = EXP2(st[1][m][1]);
            const float p6 = EXP2(st[1][m][2]);
            const float p7 = EXP2(st[1][m][3]);
            lsum[m] += ((p0 + p1) + (p2 + p3)) + ((p4 + p5) + (p6 + p7));
            H8U hh;
            hh.u[0] = pk(p0, p1); hh.u[1] = pk(p2, p3);
            hh.u[2] = pk(p4, p5); hh.u[3] = pk(p6, p7);
            pb[m] = hh.h;
        }

        // ---- O^T(full d) += V^T P^T over own kv-half dh ----
        __builtin_amdgcn_s_setprio(1);
        #pragma unroll
        for (int dt = 0; dt < 8; ++dt) {
            const int d = 16 * dt + c;
            half8 va = *(const half8*)(vcur + d * 128 + 16 * ((4 * dh + qd) ^ (d & 7)));
            #pragma unroll
            for (int m = 0; m < 4; ++m)
                o[m][dt] = __builtin_amdgcn_mfma_f32_16x16x32_f16(va, pb[m], o[m][dt], 0, 0, 0);
        }
        __builtin_amdgcn_s_setprio(0);

        __syncthreads();   // next K/V tile resident; cur free for kt+2 staging
    }

    // ---- epilogue ----
    // 1) denominators: reduce lsum over qd; merge halves via lbuf
    #pragma unroll
    for (int m = 0; m < 4; ++m) {
        lsum[m] += __shfl_xor(lsum[m], 16, 64);
        lsum[m] += __shfl_xor(lsum[m], 32, 64);
    }
    float* lbuf = (float*)smem;          // [2][256] -- kbuf free after loop
    char* const xch = smem + 32768;      // 32KB     -- vbuf free after loop
    if (qd == 0) {
        #pragma unroll
        for (int m = 0; m < 4; ++m)
            lbuf[dh * 256 + 64 * wq + 16 * m + c] = lsum[m];
    }
    __syncthreads();

    // 2) O merge: per m, each wave ships the d-half it does NOT output,
    //    reads sibling's slot for the half it DOES output.
    //    RULE #20: all o[] indices are compile-time; dh selects VALUES.
    #pragma unroll
    for (int m = 0; m < 4; ++m) {
        const int qrow = 64 * wq + 16 * m + c;
        const float invl = 1.0f / (lbuf[qrow] + lbuf[256 + qrow]);
        #pragma unroll
        for (int dtl = 0; dtl < 4; ++dtl) {   // ship the non-output half
            floatx4 ship = dh ? o[m][dtl] : o[m][dtl + 4];
            *(floatx4*)(xch + (w << 12) + (dtl << 10) + (lane << 4)) = ship;
        }
        __syncthreads();
        #pragma unroll
        for (int dtl = 0; dtl < 4; ++dtl) {   // combine + store own half
            floatx4 own = dh ? o[m][dtl + 4] : o[m][dtl];
            floatx4 r = own +
                *(const floatx4*)(xch + ((w ^ 4) << 12) + (dtl << 10) + (lane << 4));
            r[0] *= invl; r[1] *= invl; r[2] *= invl; r[3] *= invl;
            const int dt_o = 4 * dh + dtl;    // runtime in ADDRESS only: fine
            *(floatx4*)&Ob[(size_t)(q0 + qrow) * 128 + 16 * dt_o + 4 * qd] = r;
        }
        __syncthreads();   // slots reusable for next m
    }
}

extern "C" void kernel_launch(void* const* d_in, const int* in_sizes, int n_in,
                              void* d_out, int out_size, void* d_ws, size_t ws_size,
                              hipStream_t stream) {
    const float* q = (const float*)d_in[0];
    const float* k = (const float*)d_in[1];
    const float* v = (const float*)d_in[2];
    float* out = (float*)d_out;
    char* ws = (char*)d_ws;
    cvt_kernel<<<dim3(1024), dim3(256), 0, stream>>>(k, v, ws);
    fa_kernel<<<dim3(256), dim3(512), 0, stream>>>(q, out, ws);
}

// Round 7
// 227.948 us; speedup vs baseline: 2.3033x; 1.0825x over previous
//
#include <hip/hip_runtime.h>

// SDPA, static mask (kv < 2048 attended). Two-kernel plan:
//  Pass 1: K -> f16 [kv][d] rows (256B), chunk c at c ^ key(r),
//          key(r) = (r&7) ^ ((r>>1)&4); V -> f16 transposed [d][kv] via
//          LDS transpose; output chunk y of row d at y ^ (d&7).
//  Pass 2: flash attention, BM=256, 8 waves = 4 wq x 2 dh, q=64/wave.
//          R4 algebra (proven 89us, clean 210-reg codegen): wave (wq,dh)
//          computes S^T on kv-half dh (permuted-K feed -> P lane-local),
//          PV on d-half dh over full kv-64 via 32KB pex exchange.
//          NEW (T4): 3-slot K/V ring + counted vmcnt. R3/R4/R6 all ended
//          each iter in __syncthreads -> vmcnt(0) drain: all waves idle
//          until the whole next tile lands (the invariant stall across
//          90-110us). Now: prologue stages tiles 0,1; iter kt waits
//          vmcnt(4) (tile kt done, kt+1 in flight), barrier, issues tile
//          kt+2 into the slot freed at kt-1. NO vmcnt drain in the loop.
//          Safety: vmcnt completes oldest-first (m135); slot (kt+2)%3's
//          readers are all behind barrier #1; pex races bracketed by the
//          two barriers; last iter peels to vmcnt(0).
//          Spill tripwire: WRITE_SIZE > 32768 KB.

#define NT 32

typedef _Float16 half8  __attribute__((ext_vector_type(8)));
typedef __fp16   fp16x2 __attribute__((ext_vector_type(2)));
typedef float    floatx4 __attribute__((ext_vector_type(4)));
typedef unsigned int uint;
typedef uint     uintx4 __attribute__((ext_vector_type(4)));

#if __has_builtin(__builtin_amdgcn_exp2f)
#define EXP2(x) __builtin_amdgcn_exp2f(x)
#else
#define EXP2(x) exp2f(x)
#endif

union H2U { fp16x2 h; uint u; };
union H8U { uint u[4]; half8 h; };

static __device__ __forceinline__ uint pk(float a, float b) {
    H2U z; z.h = __builtin_amdgcn_cvt_pkrtz(a, b); return z.u;
}

// ws layout (bytes): Kh[32][2048][128] f16 @0 ; Vt[32][128][2048] f16 @16MB
#define KH_BH 524288u
#define VT_BASE 16777216u
#define VT_BH 524288u

#define GLOAD_LDS16(g, l)                                                     \
    __builtin_amdgcn_global_load_lds(                                         \
        (const __attribute__((address_space(1))) uint*)(const void*)(g),      \
        (__attribute__((address_space(3))) uint*)(void*)(l), 16, 0, 0)

// ---------------- Pass 1: convert + transpose, coalesced ----------------
__global__ __launch_bounds__(256)
void cvt_kernel(const float* __restrict__ K, const float* __restrict__ V,
                char* __restrict__ ws) {
    const int bid = blockIdx.x;        // 32 bh x 32 kv-tiles of 64
    const int bh  = bid >> 5;
    const int kv0 = (bid & 31) * 64;
    const int t   = threadIdx.x;

    const float* Kb = K + (size_t)bh * 4096 * 128 + (size_t)kv0 * 128;
    const float* Vb = V + (size_t)bh * 4096 * 128 + (size_t)kv0 * 128;
    char* Khb = ws + (size_t)bh * KH_BH + (size_t)kv0 * 256;
    char* Vtb = ws + VT_BASE + (size_t)bh * VT_BH;

    // --- K: 16 lanes per 256B row; chunk c16 stored at c16 ^ key(r).
    {
        const int c16 = t & 15;
        #pragma unroll
        for (int rnd = 0; rnd < 4; ++rnd) {
            const int r = rnd * 16 + (t >> 4);
            const float* src = Kb + (size_t)r * 128 + c16 * 8;
            floatx4 a = *(const floatx4*)src;
            floatx4 b = *(const floatx4*)(src + 4);
            H8U hh;
            hh.u[0] = pk(a[0], a[1]); hh.u[1] = pk(a[2], a[3]);
            hh.u[2] = pk(b[0], b[1]); hh.u[3] = pk(b[2], b[3]);
            const int key = (r & 7) ^ ((r >> 1) & 4);
            *(half8*)(Khb + r * 256 + 16 * (c16 ^ key)) = hh.h;
        }
    }

    // --- V transpose via LDS. U[d][col] uints; col-group includes d>>2 so
    // stage-A write banks spread. Stage-B undoes it; global layout stays:
    // chunk y of row d at y ^ (d&7).
    __shared__ __align__(16) uint U[128 * 32];
    {
        const int dpos = t & 31;        // d / 4
        const int k3   = t >> 5;        // kv-pair within round
        #pragma unroll
        for (int rnd = 0; rnd < 4; ++rnd) {
            const int kvp = rnd * 8 + k3;   // kv pair index 0..31
            floatx4 a = *(const floatx4*)(Vb + (size_t)(2 * kvp) * 128 + 4 * dpos);
            floatx4 b = *(const floatx4*)(Vb + (size_t)(2 * kvp + 1) * 128 + 4 * dpos);
            #pragma unroll
            for (int e = 0; e < 4; ++e) {
                const int d   = 4 * dpos + e;
                const int col = (kvp & 3) |
                                ((((kvp >> 2) ^ d ^ (d >> 2)) & 7) << 2);
                U[d * 32 + col] = pk(a[e], b[e]);
            }
        }
    }
    __syncthreads();
    // Stage B: 8 lanes cover a full 128B Vt row.
    {
        const int s = t & 7;
        #pragma unroll
        for (int rnd = 0; rnd < 4; ++rnd) {
            const int d = rnd * 32 + (t >> 3);
            uintx4 u = *(const uintx4*)&U[d * 32 + 4 * s];
            *(uintx4*)(Vtb + (size_t)d * 4096 + (size_t)kv0 * 2 +
                       16 * ((s ^ (d >> 2)) & 7)) = u;
        }
    }
}

// ---------------- Pass 2: flash attention ----------------
__global__ __launch_bounds__(512, 2)
void fa_kernel(const float* __restrict__ Q, float* __restrict__ O,
               const char* __restrict__ ws) {
    const float SCALE = 0.08838834764831845f * 1.4426950408889634f;

    __shared__ __align__(16) char smem[131072];
    // [0,96K): 3 slots of 32K (K 16K | V 16K)   [96K,128K): pex (lbuf reuse)

    const int t    = threadIdx.x;
    const int lane = t & 63;
    const int w    = t >> 6;        // 0..7
    const int wq   = w & 3;         // q-group (64 rows)
    const int dh   = w >> 2;        // kv-half (S^T) == d-half (PV)
    const int c    = lane & 15;
    const int qd   = lane >> 4;

    const int idx  = blockIdx.x;    // 256 = 8 xcd x 8 qt x 4 bh-group
    const int xcd  = idx & 7;
    const int slot = idx >> 3;      // 0..31
    const int qt   = slot & 7;
    const int bh   = xcd + 8 * (slot >> 3);
    const int q0   = qt * 256;

    const float* Qb  = Q + (size_t)bh * 2048 * 128;
    float*       Ob  = O + (size_t)bh * 2048 * 128;
    const char*  Khb = ws + (size_t)bh * KH_BH;
    const char*  Vtb = ws + VT_BASE + (size_t)bh * VT_BH;

    char* const pexb = smem + 98304;

    // K tile 16KB: 16 insts of 1KB, inst i = rows 4i..4i+3 (linear dst)
    #define ISSUE_K(kv0_, dst_)                                                  \
        { _Pragma("unroll")                                                      \
          for (int j = 0; j < 2; ++j) {                                          \
              const int i = 2 * w + j;                                           \
              const char* g = Khb + (size_t)(kv0_) * 256 +                       \
                              (size_t)(4 * i + (lane >> 4)) * 256 + (lane & 15) * 16; \
              GLOAD_LDS16(g, (dst_) + i * 1024); } }
    // V tile 16KB: inst i = d-rows 8i..8i+7 (128B each)
    #define ISSUE_V(kv0_, dst_)                                                  \
        { _Pragma("unroll")                                                      \
          for (int j = 0; j < 2; ++j) {                                          \
              const int i = 2 * w + j;                                           \
              const char* g = Vtb + (size_t)(8 * i + (lane >> 3)) * 4096 +       \
                              (size_t)(kv0_) * 2 + (lane & 7) * 16;              \
              GLOAD_LDS16(g, (dst_) + i * 1024); } }

    // Prologue staging: tiles 0 -> slot0, 1 -> slot1 (4 insts/wave each)
    ISSUE_K(0,  smem);
    ISSUE_V(0,  smem + 16384);
    ISSUE_K(64, smem + 32768);
    ISSUE_V(64, smem + 49152);

    // ---- Q B-frags: B[k=32s+8qd+j][n=16m+c], scale folded; q=64/wave.
    // Q loads are NEWER than staging on vmcnt; all consumed here, so at
    // loop entry outstanding = staging only (accounting below exact).
    half8 bq[4][4];
    #pragma unroll
    for (int m = 0; m < 4; ++m) {
        #pragma unroll
        for (int s = 0; s < 4; ++s) {
            const int row = q0 + 64 * wq + 16 * m + c;
            const float* p = Qb + (size_t)row * 128 + 32 * s + 8 * qd;
            floatx4 x = *(const floatx4*)p;
            floatx4 y = *(const floatx4*)(p + 4);
            H8U hh;
            hh.u[0] = pk(x[0] * SCALE, x[1] * SCALE);
            hh.u[1] = pk(x[2] * SCALE, x[3] * SCALE);
            hh.u[2] = pk(y[0] * SCALE, y[1] * SCALE);
            hh.u[3] = pk(y[2] * SCALE, y[3] * SCALE);
            bq[m][s] = hh.h;
        }
    }

    // O^T for d-half dh, full kv: lane (c,qd): q=64wq+16m+c, d=64dh+16dt+4qd+r
    floatx4 o[4][4];
    float lsum[4] = {0.f, 0.f, 0.f, 0.f};
    #pragma unroll
    for (int m = 0; m < 4; ++m)
        #pragma unroll
        for (int dt = 0; dt < 4; ++dt) o[m][dt] = (floatx4){0.f, 0.f, 0.f, 0.f};

    // P exchange slots: [w][m] 1KB blocks; lane chunk at qd*256 + c*16
    char* const pex_own = pexb + (w << 12) + (qd << 8) + (c << 4);
    const char* const pex_sib = pexb + ((w ^ 4) << 12) + (qd << 8) + (c << 4);

    int slc = 0;    // byte-slot of tile kt:   (kt%3)*32768
    int sli = 2;    // byte-slot of tile kt+2: ((kt+2)%3)*32768

    for (int kt = 0; kt < NT; ++kt) {
        // T4: counted wait -- tile kt's 4 loads done, tile kt+1's stay in
        // flight. Only the final iteration drains.
        if (kt + 1 < NT) { asm volatile("s_waitcnt vmcnt(4)" ::: "memory"); }
        else             { asm volatile("s_waitcnt vmcnt(0)" ::: "memory"); }
        __builtin_amdgcn_s_barrier();   // tile kt fully resident (all waves
        asm volatile("" ::: "memory");  // waited); prior iter fully consumed

        if (kt + 2 < NT) {   // stage tile kt+2 into slot freed at iter kt-1
            char* ib = smem + sli * 32768;
            ISSUE_K((kt + 2) * 64, ib);
            ISSUE_V((kt + 2) * 64, ib + 16384);
        }
        char* kcur = smem + slc * 32768;
        char* vcur = kcur + 16384;

        // ---- S^T = K Q^T on kv-half dh, permuted K-row feed:
        // C row i fed with K row 32dh + 8(i>>2) + 4g + (i&3), so lane
        // (c,qd) reg (g,r) holds kv = 32dh + 8qd + 4g + r (lane-local P).
        floatx4 st[2][4];
        #pragma unroll
        for (int g = 0; g < 2; ++g)
            #pragma unroll
            for (int m = 0; m < 4; ++m) st[g][m] = (floatx4){0.f, 0.f, 0.f, 0.f};

        __builtin_amdgcn_s_setprio(1);
        #pragma unroll
        for (int g = 0; g < 2; ++g) {
            const int row = 32 * dh + 8 * (c >> 2) + 4 * g + (c & 3);
            const int key = (row & 7) ^ ((row >> 1) & 4);
            #pragma unroll
            for (int s = 0; s < 4; ++s) {
                half8 ka = *(const half8*)(kcur + row * 256 + 16 * ((4 * s + qd) ^ key));
                #pragma unroll
                for (int m = 0; m < 4; ++m)
                    st[g][m] = __builtin_amdgcn_mfma_f32_16x16x32_f16(ka, bq[m][s], st[g][m], 0, 0, 0);
            }
        }
        __builtin_amdgcn_s_setprio(0);

        // ---- softmax (fixed m=0, exp2 domain): pb[m] el j = P[kv=32dh+8qd+j]
        half8 pb[4];
        #pragma unroll
        for (int m = 0; m < 4; ++m) {
            const float p0 = EXP2(st[0][m][0]);
            const float p1 = EXP2(st[0][m][1]);
            const float p2 = EXP2(st[0][m][2]);
            const float p3 = EXP2(st[0][m][3]);
            const float p4 = EXP2(st[1][m][0]);
            const float p5 = EXP2(st[1][m][1]);
            const float p6 = EXP2(st[1][m][2]);
            const float p7 = EXP2(st[1][m][3]);
            lsum[m] += ((p0 + p1) + (p2 + p3)) + ((p4 + p5) + (p6 + p7));
            H8U hh;
            hh.u[0] = pk(p0, p1); hh.u[1] = pk(p2, p3);
            hh.u[2] = pk(p4, p5); hh.u[3] = pk(p6, p7);
            pb[m] = hh.h;
            // own half -> Pex (contiguous 1KB per store inst: conflict-free)
            *(half8*)(pex_own + (m << 10)) = pb[m];
        }

        // barrier #2: P visible; vmcnt NOT drained (prefetch keeps flying)
        asm volatile("s_waitcnt lgkmcnt(0)" ::: "memory");
        __builtin_amdgcn_s_barrier();
        asm volatile("" ::: "memory");

        half8 ps[4];
        #pragma unroll
        for (int m = 0; m < 4; ++m)
            ps[m] = *(const half8*)(pex_sib + (m << 10));

        // ---- O^T(d-half dh) += V^T P^T over full kv-64 ----
        __builtin_amdgcn_s_setprio(1);
        #pragma unroll
        for (int dt = 0; dt < 4; ++dt) {
            const int d = 64 * dh + 16 * dt + c;
            half8 va_own = *(const half8*)(vcur + d * 128 + 16 * ((4 * dh + qd) ^ (d & 7)));
            half8 va_sib = *(const half8*)(vcur + d * 128 + 16 * ((4 * (dh ^ 1) + qd) ^ (d & 7)));
            #pragma unroll
            for (int m = 0; m < 4; ++m) {
                o[m][dt] = __builtin_amdgcn_mfma_f32_16x16x32_f16(va_own, pb[m], o[m][dt], 0, 0, 0);
                o[m][dt] = __builtin_amdgcn_mfma_f32_16x16x32_f16(va_sib, ps[m], o[m][dt], 0, 0, 0);
            }
        }
        __builtin_amdgcn_s_setprio(0);

        slc = (slc == 2) ? 0 : slc + 1;
        sli = (sli == 2) ? 0 : sli + 1;
        // NO end-of-iter drain: next iter's barrier #1 is the only sync.
    }

    __syncthreads();   // loop fully done in all waves before pex -> lbuf

    // ---- epilogue: reduce lsum over qd; merge kv-halves via lbuf ----
    #pragma unroll
    for (int m = 0; m < 4; ++m) {
        lsum[m] += __shfl_xor(lsum[m], 16, 64);
        lsum[m] += __shfl_xor(lsum[m], 32, 64);
    }
    float* lbuf = (float*)pexb;   // [2][256]
    if (qd == 0) {
        #pragma unroll
        for (int m = 0; m < 4; ++m)
            lbuf[dh * 256 + 64 * wq + 16 * m + c] = lsum[m];
    }
    __syncthreads();
    #pragma unroll
    for (int m = 0; m < 4; ++m) {
        const int qrow = 64 * wq + 16 * m + c;
        const float invl = 1.0f / (lbuf[qrow] + lbuf[256 + qrow]);
        #pragma unroll
        for (int dt = 0; dt < 4; ++dt) {
            floatx4 r = o[m][dt];
            r[0] *= invl; r[1] *= invl; r[2] *= invl; r[3] *= invl;
            *(floatx4*)&Ob[(size_t)(q0 + qrow) * 128 + 64 * dh + 16 * dt + 4 * qd] = r;
        }
    }
}

extern "C" void kernel_launch(void* const* d_in, const int* in_sizes, int n_in,
                              void* d_out, int out_size, void* d_ws, size_t ws_size,
                              hipStream_t stream) {
    const float* q = (const float*)d_in[0];
    const float* k = (const float*)d_in[1];
    const float* v = (const float*)d_in[2];
    float* out = (float*)d_out;
    char* ws = (char*)d_ws;
    cvt_kernel<<<dim3(1024), dim3(256), 0, stream>>>(k, v, ws);
    fa_kernel<<<dim3(256), dim3(512), 0, stream>>>(q, out, ws);
}